// Round 4
// baseline (148.905 us; speedup 1.0000x reference)
//
#include <hip/hip_runtime.h>
#include <math.h>

// SystemsOfSprings, round 5: round-1 layout (ONE node per lane, one slot per
// thread -- the fastest measured) + DPP/rsqrt chain-shorteners + NON-TEMPORAL
// full-line stores.
//
// Evidence trail:
//  * r1 (1 node/thread, ds_swizzle, sqrt+div): 42 us. WRITE exactly 64 MB,
//    FETCH 49 MB, VALU 33%, HBM 34%. Nothing saturated.
//  * r2 (2 pairs/thread contiguous + nt): partial-line wave ops -> nt stores
//    write-amplified (64->102 MB). The hint wasn't the bug; the layout was.
//  * r3 (4 slots @ 16 MB stride): power-of-two set aliasing -> WRITE 85 MB.
//  * r4 (4 slots block-local): WRITE back to exactly 64 MB, coalescing
//    perfect, VALU down to 13% (DPP+rsqrt work) -- yet 47 us > r1's 42.
//    => per-thread MLP is NOT the lever. Three rounds of it never helped.
//  * Constant across ALL rounds: FETCH pinned at ~49 MB = half the 96 MB
//    logical read, while the 160 MB working set fits in the 256 MB L3.
//    Theory: the 64 MB/iter plain write stream keeps evicting x/u from L3;
//    the HBM-miss half of each wave's 8-line load span is the serializer.
//  * => this round: keep r1's layout (fastest), make stores `nt` so out
//    streams past L3 and x/u become fully L3-resident. Falsifiable via
//    FETCH_SIZE: predict 49 MB -> <15 MB steady-state, WRITE stays 65536 KB.
//
// Physics per node n: a_n = -(p_n - t_n) - 2 v_n - sum_d (r_d - L_d) * e_d
// (goal force collapsed analytically: cos(atan2(y,x)) = x/r; r==0 edge
// follows atan2(0,0)=0 -> c=1, s=0).

#define TS 0.05f
#define L9 4.2720018727f  // sqrt(4^2 + 1.5^2) = sqrt(18.25)

typedef float f4v __attribute__((ext_vector_type(4)));

template <int CTRL>
__device__ __forceinline__ float dpp_qp(float v) {
    // quad_perm DPP: full row/bank masks, bound_ctrl=1. 0xB1=[1,0,3,2] (xor1),
    // 0x4E=[2,3,0,1] (xor2), 0x1B=[3,2,1,0] (xor3). Node groups are aligned
    // 4-lane groups since thread g holds node g and g%4 == lane%4.
    return __int_as_float(__builtin_amdgcn_update_dpp(
        0, __float_as_int(v), CTRL, 0xF, 0xF, true));
}

__device__ __forceinline__ void edge_acc(float dx, float dy, float L,
                                         float& ax, float& ay) {
    float d2   = dx * dx + dy * dy;
    bool  nz   = d2 > 0.f;
    float invr = nz ? rsqrtf(d2) : 0.f;
    float r    = d2 * invr;             // sqrt(d2); 0 when d2==0
    float c    = nz ? dx * invr : 1.f;  // atan2(0,0)=0 -> cos=1
    float sn   = dy * invr;             //              -> sin=0
    float Fk   = r - L;
    ax -= Fk * c;
    ay -= Fk * sn;
}

__global__ __launch_bounds__(256) void springs_nt_kernel(
    const float* __restrict__ x,
    const float* __restrict__ u,
    float* __restrict__ out,
    int N)  // N = total nodes = B*4
{
    int g = blockIdx.x * blockDim.x + threadIdx.x;
    if (g >= N) return;

    float4 s  = reinterpret_cast<const float4*>(x)[g];  // px,py,vx,vy
    float2 uc = reinterpret_cast<const float2*>(u)[g];  // control pair

    int node = g & 3;
    float xt = (node == 1 || node == 2) ? -2.f : 2.f;
    float yt = (node >= 2) ? -2.f : 2.f;

    // Goal force, analytically collapsed: a = -(p - t) - 2 v
    float ax = -(s.x - xt) - 2.f * s.z;
    float ay = -(s.y - yt) - 2.f * s.w;

    // Neighbors: nodes 0..3 of this system live in the aligned 4-lane group.
    float qx1 = dpp_qp<0xB1>(s.x), qy1 = dpp_qp<0xB1>(s.y);
    float qx2 = dpp_qp<0x4E>(s.x), qy2 = dpp_qp<0x4E>(s.y);
    float qx3 = dpp_qp<0x1B>(s.x), qy3 = dpp_qp<0x1B>(s.y);

    edge_acc(s.x - qx1, s.y - qy1, 4.0f, ax, ay);  // xor 1: (0,1),(2,3) L=4
    edge_acc(s.x - qx2, s.y - qy2, L9,   ax, ay);  // xor 2: (0,2),(1,3) L=sqrt(18.25)
    edge_acc(s.x - qx3, s.y - qy3, 1.5f, ax, ay);  // xor 3: (1,2),(3,0) L=1.5

    f4v r;
    r.x = s.x + TS * s.z;
    r.y = s.y + TS * s.w;
    r.z = s.z + TS * (ax + uc.x);
    r.w = s.w + TS * (ay + uc.y);

    // Full-line-coalesced non-temporal store: each wave writes a contiguous
    // 1 KB span, so `nt` streams whole lines past L2/L3 without the r2
    // partial-line write amplification. Keeps L3 capacity for x,u.
    __builtin_nontemporal_store(
        r, reinterpret_cast<f4v*>(out) + g);
}

extern "C" void kernel_launch(void* const* d_in, const int* in_sizes, int n_in,
                              void* d_out, int out_size, void* d_ws, size_t ws_size,
                              hipStream_t stream) {
    // Inputs (setup_inputs order): t (scalar), x (B*16 f32), u (B*8 f32),
    // w (16 f32, unused), xbar (16 f32, constant baked in).
    const float* x = (const float*)d_in[1];
    const float* u = (const float*)d_in[2];
    float* out = (float*)d_out;

    int N = in_sizes[1] / 4;  // total nodes = B*4
    int block = 256;
    int grid = (N + block - 1) / block;
    springs_nt_kernel<<<grid, block, 0, stream>>>(x, u, out, N);
}

// Round 5
// 144.790 us; speedup vs baseline: 1.0284x; 1.0284x over previous
//
#include <hip/hip_runtime.h>
#include <math.h>

// SystemsOfSprings, round 6: r5 kernel (1 node/lane, DPP quad_perm, rsqrt,
// nt stores) with NON-TEMPORAL LOADS on x and u as well.
//
// Evidence trail:
//  * r1 42.8us / r4 47.4us / r5 42.0us -- ALU chain length (33%->16% VALU),
//    per-thread MLP (1x vs 4x), and store cache hints all change NOTHING.
//  * FETCH_SIZE pinned at 49 MB = half the 96 MB logical read in EVERY round,
//    invariant to layout, MLP, and nt-stores (r5 falsified the theory that
//    our own write stream caused the evictions).
//  * Remaining consistent model: ~50% of read lines hit the MALL, 50% miss,
//    interleaved at 128B line granularity (set by MALL hashing + harness
//    re-poison traffic, outside kernel control). HBM then services a
//    line-scattered read pattern -> row-buffer locality destroyed ->
//    2.8 TB/s effective (44% of the 6.3 TB/s streaming ceiling) with no
//    on-chip pipe saturated. Matches all five rounds.
//  * This round flips the only untouched corner: READ-side cache policy.
//    nt loads no-allocate in L2/MALL -> steady state drifts to all-miss ->
//    reads become pure sequential HBM streams. 160 MB at near-streaming
//    mixed-rate ~5-6 TB/s => ~28-32 us.
//  * Falsifiable: FETCH_SIZE must jump 49 -> ~96 MB (proves nt reaches the
//    MALL). dur down => theory confirmed; dur up to ~55-60 => reads were
//    rate-limited regardless, revert to r5 and call ~42 us the structural
//    ceiling for this harness-cache regime.
//
// Physics per node n: a_n = -(p_n - t_n) - 2 v_n - sum_d (r_d - L_d) * e_d
// (goal force collapsed analytically: cos(atan2(y,x)) = x/r; r==0 edge
// follows atan2(0,0)=0 -> c=1, s=0).

#define TS 0.05f
#define L9 4.2720018727f  // sqrt(4^2 + 1.5^2) = sqrt(18.25)

typedef float f4v __attribute__((ext_vector_type(4)));
typedef float f2v __attribute__((ext_vector_type(2)));

template <int CTRL>
__device__ __forceinline__ float dpp_qp(float v) {
    // quad_perm DPP: full row/bank masks, bound_ctrl=1. 0xB1=[1,0,3,2] (xor1),
    // 0x4E=[2,3,0,1] (xor2), 0x1B=[3,2,1,0] (xor3). Node groups are aligned
    // 4-lane groups since thread g holds node g and g%4 == lane%4.
    return __int_as_float(__builtin_amdgcn_update_dpp(
        0, __float_as_int(v), CTRL, 0xF, 0xF, true));
}

__device__ __forceinline__ void edge_acc(float dx, float dy, float L,
                                         float& ax, float& ay) {
    float d2   = dx * dx + dy * dy;
    bool  nz   = d2 > 0.f;
    float invr = nz ? rsqrtf(d2) : 0.f;
    float r    = d2 * invr;             // sqrt(d2); 0 when d2==0
    float c    = nz ? dx * invr : 1.f;  // atan2(0,0)=0 -> cos=1
    float sn   = dy * invr;             //              -> sin=0
    float Fk   = r - L;
    ax -= Fk * c;
    ay -= Fk * sn;
}

__global__ __launch_bounds__(256) void springs_ntrw_kernel(
    const float* __restrict__ x,
    const float* __restrict__ u,
    float* __restrict__ out,
    int N)  // N = total nodes = B*4
{
    int g = blockIdx.x * blockDim.x + threadIdx.x;
    if (g >= N) return;

    // Non-temporal loads: no-allocate in L2/MALL so the read streams stay
    // sequential at the HBM (avoid the half-hit line-scattered regime).
    f4v sv = __builtin_nontemporal_load(reinterpret_cast<const f4v*>(x) + g);
    f2v cv = __builtin_nontemporal_load(reinterpret_cast<const f2v*>(u) + g);

    float px = sv.x, py = sv.y, vx = sv.z, vy = sv.w;

    int node = g & 3;
    float xt = (node == 1 || node == 2) ? -2.f : 2.f;
    float yt = (node >= 2) ? -2.f : 2.f;

    // Goal force, analytically collapsed: a = -(p - t) - 2 v
    float ax = -(px - xt) - 2.f * vx;
    float ay = -(py - yt) - 2.f * vy;

    // Neighbors: nodes 0..3 of this system live in the aligned 4-lane group.
    float qx1 = dpp_qp<0xB1>(px), qy1 = dpp_qp<0xB1>(py);
    float qx2 = dpp_qp<0x4E>(px), qy2 = dpp_qp<0x4E>(py);
    float qx3 = dpp_qp<0x1B>(px), qy3 = dpp_qp<0x1B>(py);

    edge_acc(px - qx1, py - qy1, 4.0f, ax, ay);  // xor 1: (0,1),(2,3) L=4
    edge_acc(px - qx2, py - qy2, L9,   ax, ay);  // xor 2: (0,2),(1,3) L=sqrt(18.25)
    edge_acc(px - qx3, py - qy3, 1.5f, ax, ay);  // xor 3: (1,2),(3,0) L=1.5

    f4v r;
    r.x = px + TS * vx;
    r.y = py + TS * vy;
    r.z = vx + TS * (ax + cv.x);
    r.w = vy + TS * (ay + cv.y);

    // Full-line-coalesced non-temporal store (r5: WRITE stays exactly 64 MB).
    __builtin_nontemporal_store(r, reinterpret_cast<f4v*>(out) + g);
}

extern "C" void kernel_launch(void* const* d_in, const int* in_sizes, int n_in,
                              void* d_out, int out_size, void* d_ws, size_t ws_size,
                              hipStream_t stream) {
    // Inputs (setup_inputs order): t (scalar), x (B*16 f32), u (B*8 f32),
    // w (16 f32, unused), xbar (16 f32, constant baked in).
    const float* x = (const float*)d_in[1];
    const float* u = (const float*)d_in[2];
    float* out = (float*)d_out;

    int N = in_sizes[1] / 4;  // total nodes = B*4
    int block = 256;
    int grid = (N + block - 1) / block;
    springs_ntrw_kernel<<<grid, block, 0, stream>>>(x, u, out, N);
}